// Round 1
// baseline (800.428 us; speedup 1.0000x reference)
//
#include <hip/hip_runtime.h>
#include <math.h>

#define HID 128
#define NGRAPH 4

typedef int idx_t;  // harness passes integer inputs as int32

// ---------------- degree histogram ----------------
__global__ __launch_bounds__(256) void k_count(const idx_t* __restrict__ dst,
                                               int* __restrict__ cnt, int E) {
  int e = blockIdx.x * 256 + threadIdx.x;
  if (e < E) atomicAdd(&cnt[dst[e]], 1);
}

// ---------------- exclusive scan (single block) + dinv ----------------
__global__ __launch_bounds__(1024) void k_scan(const int* __restrict__ cnt,
                                               int* __restrict__ off,
                                               float* __restrict__ dinv, int n) {
  __shared__ int s[1024];
  int tid = threadIdx.x;
  int carry = 0;
  for (int base = 0; base < n; base += 1024) {
    int idx = base + tid;
    int v = (idx < n) ? cnt[idx] : 0;
    if (idx < n) dinv[idx] = 1.0f / sqrtf((float)v + 1.0f);  // deg = cnt + self-loop
    s[tid] = v;
    __syncthreads();
    for (int ofs = 1; ofs < 1024; ofs <<= 1) {
      int t = (tid >= ofs) ? s[tid - ofs] : 0;
      __syncthreads();
      s[tid] += t;
      __syncthreads();
    }
    if (idx < n) off[idx] = carry + s[tid] - v;  // exclusive
    carry += s[1023];
    __syncthreads();
  }
  if (tid == 0) off[n] = carry;
}

// ---------------- CSR fill ----------------
__global__ __launch_bounds__(256) void k_fill(const idx_t* __restrict__ src,
                                              const idx_t* __restrict__ dst,
                                              const int* __restrict__ off,
                                              int* __restrict__ fillc,
                                              idx_t* __restrict__ cidx, int E) {
  int e = blockIdx.x * 256 + threadIdx.x;
  if (e < E) {
    int d = dst[e];
    int p = atomicAdd(&fillc[d], 1);
    cidx[off[d] + p] = src[e];
  }
}

// ---------------- fp32 GEMM: Y[M][128] = X[M][K] @ W[K][128] ----------------
template <int K>
__global__ __launch_bounds__(256) void k_gemm(const float* __restrict__ X,
                                              const float* __restrict__ W,
                                              float* __restrict__ Y, int M) {
  constexpr int BM = 64, BK = 32;
  __shared__ float As[BM][BK + 1];   // +1 pad: staging-write conflicts ~2-way
  __shared__ float Bs[BK][HID];
  int tid = threadIdx.x;
  int tr = tid >> 5, tc = tid & 31;  // 8 row-groups x 32 col-groups
  int row0 = blockIdx.x * BM;
  float acc[8][4] = {};
  for (int k0 = 0; k0 < K; k0 += BK) {
    // stage A: 64 rows x 32 k  (512 float4)
#pragma unroll
    for (int p = 0; p < 2; ++p) {
      int i = tid + p * 256;
      int r = i >> 3, kq = i & 7;
      float4 v = make_float4(0.f, 0.f, 0.f, 0.f);
      if (row0 + r < M)
        v = *reinterpret_cast<const float4*>(&X[(size_t)(row0 + r) * K + k0 + kq * 4]);
      As[r][kq * 4 + 0] = v.x; As[r][kq * 4 + 1] = v.y;
      As[r][kq * 4 + 2] = v.z; As[r][kq * 4 + 3] = v.w;
    }
    // stage B: 32 k x 128 cols (1024 float4)
#pragma unroll
    for (int p = 0; p < 4; ++p) {
      int i = tid + p * 256;
      int kk = i >> 5, c4 = i & 31;
      float4 v = *reinterpret_cast<const float4*>(&W[(size_t)(k0 + kk) * HID + c4 * 4]);
      *reinterpret_cast<float4*>(&Bs[kk][c4 * 4]) = v;
    }
    __syncthreads();
#pragma unroll
    for (int k = 0; k < BK; ++k) {
      float b[4], a[8];
#pragma unroll
      for (int j = 0; j < 4; ++j) b[j] = Bs[k][tc * 4 + j];
#pragma unroll
      for (int i = 0; i < 8; ++i) a[i] = As[tr * 8 + i][k];  // 2 addrs/wave: broadcast
#pragma unroll
      for (int i = 0; i < 8; ++i)
#pragma unroll
        for (int j = 0; j < 4; ++j) acc[i][j] = fmaf(a[i], b[j], acc[i][j]);
    }
    __syncthreads();
  }
#pragma unroll
  for (int i = 0; i < 8; ++i) {
    int r = row0 + tr * 8 + i;
    if (r < M)
      *reinterpret_cast<float4*>(&Y[(size_t)r * HID + tc * 4]) =
          make_float4(acc[i][0], acc[i][1], acc[i][2], acc[i][3]);
  }
}

// ---------------- per-node gather-aggregate + bias + ReLU ----------------
// out[v] = relu( b + dinv[v]^2*xw[v] + sum_{u in in(v)} dinv[u]*dinv[v]*xw[u] )
__global__ __launch_bounds__(256) void k_agg(const float* __restrict__ xw,
                                             const float* __restrict__ dinv,
                                             const int* __restrict__ off,
                                             const idx_t* __restrict__ cidx,
                                             const float* __restrict__ bias,
                                             float* __restrict__ out, int n) {
  int v = blockIdx.x * 4 + (threadIdx.x >> 6);
  if (v >= n) return;
  int lane = threadIdx.x & 63;
  float dv = dinv[v];
  float2 self = *reinterpret_cast<const float2*>(&xw[(size_t)v * HID + lane * 2]);
  float2 acc;
  acc.x = dv * dv * self.x;
  acc.y = dv * dv * self.y;
  int j0 = off[v], j1 = off[v + 1];
  for (int j = j0; j < j1; ++j) {
    int u = cidx[j];                    // wave-uniform
    float w = dinv[u] * dv;             // wave-uniform
    float2 m = *reinterpret_cast<const float2*>(&xw[(size_t)u * HID + lane * 2]);
    acc.x = fmaf(w, m.x, acc.x);
    acc.y = fmaf(w, m.y, acc.y);
  }
  float2 b = *reinterpret_cast<const float2*>(&bias[lane * 2]);
  float2 o;
  o.x = fmaxf(acc.x + b.x, 0.0f);
  o.y = fmaxf(acc.y + b.y, 0.0f);
  *reinterpret_cast<float2*>(&out[(size_t)v * HID + lane * 2]) = o;
}

// ---------------- per-graph node counts ----------------
__global__ __launch_bounds__(256) void k_gcnt(const idx_t* __restrict__ batch,
                                              int* __restrict__ gcnt, int n) {
  __shared__ int h[NGRAPH];
  int tid = threadIdx.x;
  if (tid < NGRAPH) h[tid] = 0;
  __syncthreads();
  int i = blockIdx.x * 256 + tid;
  if (i < n) atomicAdd(&h[batch[i]], 1);
  __syncthreads();
  if (tid < NGRAPH && h[tid]) atomicAdd(&gcnt[tid], h[tid]);
}

// ---------------- segment max+sum pooling (batch sorted) ----------------
__global__ __launch_bounds__(128) void k_pool(const float* __restrict__ h,
                                              const idx_t* __restrict__ batch,
                                              float* __restrict__ gmax,
                                              float* __restrict__ gsum, int n) {
  int f = threadIdx.x;
  int v0 = blockIdx.x * 128;
  int cur = -1;
  float mx = 0.f, sm = 0.f;
  for (int i = 0; i < 128; ++i) {
    int v = v0 + i;
    if (v >= n) break;
    int g = batch[v];
    if (g != cur) {
      if (cur >= 0) {
        atomicMax((int*)&gmax[cur * HID + f], __float_as_int(mx));  // h>=0: int-order ok
        atomicAdd(&gsum[cur * HID + f], sm);
      }
      cur = g; mx = 0.f; sm = 0.f;
    }
    float val = h[(size_t)v * HID + f];
    mx = fmaxf(mx, val);
    sm += val;
  }
  if (cur >= 0) {
    atomicMax((int*)&gmax[cur * HID + f], __float_as_int(mx));
    atomicAdd(&gsum[cur * HID + f], sm);
  }
}

// ---------------- tiny MLP head (one block) ----------------
__global__ __launch_bounds__(256) void k_mlp(const float* __restrict__ gmax,
                                             const float* __restrict__ gsum,
                                             const int* __restrict__ gcnt,
                                             const float* __restrict__ Wl1,
                                             const float* __restrict__ bl1,
                                             const float* __restrict__ Wl2,
                                             const float* __restrict__ bl2,
                                             const float* __restrict__ Wl3,
                                             const float* __restrict__ bl3,
                                             float* __restrict__ out) {
  __shared__ float G[NGRAPH][2 * HID];
  __shared__ float H1[NGRAPH][HID];
  __shared__ float H2[NGRAPH][HID / 2];
  int t = threadIdx.x;
  for (int i = t; i < NGRAPH * 2 * HID; i += 256) {
    int gi = i >> 8, j = i & 255;
    float val;
    if (j < HID) val = gmax[gi * HID + j];
    else val = gsum[gi * HID + (j - HID)] / fmaxf((float)gcnt[gi], 1.0f);
    G[gi][j] = val;
  }
  __syncthreads();
  for (int i = t; i < NGRAPH * HID; i += 256) {
    int gi = i >> 7, j = i & 127;
    float a = bl1[j];
    for (int k = 0; k < 2 * HID; ++k) a = fmaf(G[gi][k], Wl1[k * HID + j], a);
    H1[gi][j] = fmaxf(a, 0.f);
  }
  __syncthreads();
  {
    int gi = t >> 6, j = t & 63;  // 4*64 = 256 outputs, exactly one per thread
    float a = bl2[j];
    for (int k = 0; k < HID; ++k) a = fmaf(H1[gi][k], Wl2[k * 64 + j], a);
    H2[gi][j] = fmaxf(a, 0.f);
  }
  __syncthreads();
  if (t < NGRAPH) {
    float a = bl3[0];
    for (int k = 0; k < 64; ++k) a = fmaf(H2[t][k], Wl3[k], a);
    out[t] = fminf(a, 5.0f);
  }
}

extern "C" void kernel_launch(void* const* d_in, const int* in_sizes, int n_in,
                              void* d_out, int out_size, void* d_ws, size_t ws_size,
                              hipStream_t stream) {
  const float* x   = (const float*)d_in[0];
  const idx_t* ei  = (const idx_t*)d_in[1];
  const idx_t* bat = (const idx_t*)d_in[2];
  const float* W0 = (const float*)d_in[3];  const float* b0 = (const float*)d_in[4];
  const float* W1 = (const float*)d_in[5];  const float* b1 = (const float*)d_in[6];
  const float* W2 = (const float*)d_in[7];  const float* b2 = (const float*)d_in[8];
  const float* Wl1 = (const float*)d_in[9];  const float* bl1 = (const float*)d_in[10];
  const float* Wl2 = (const float*)d_in[11]; const float* bl2 = (const float*)d_in[12];
  const float* Wl3 = (const float*)d_in[13]; const float* bl3 = (const float*)d_in[14];
  float* out = (float*)d_out;

  const int N = in_sizes[2];        // 50000 nodes (batch array length)
  const int E = in_sizes[1] / 2;    // 800000 edges
  const idx_t* srcv = ei;           // edge_index[0]
  const idx_t* dstv = ei + E;       // edge_index[1]

  // workspace carve-up (~55 MB)
  char* ws = (char*)d_ws;
  size_t o = 0;
  auto alloc = [&](size_t bytes) -> void* {
    void* p = ws + o;
    o = (o + bytes + 255) & ~(size_t)255;
    return p;
  };
  float* bufA = (float*)alloc((size_t)N * HID * 4);   // xw
  float* bufB = (float*)alloc((size_t)N * HID * 4);   // h (post-relu)
  float* dinv = (float*)alloc((size_t)N * 4);
  int* cnt    = (int*)alloc((size_t)N * 4);
  int* off    = (int*)alloc((size_t)(N + 1) * 4);
  int* fillc  = (int*)alloc((size_t)N * 4);
  idx_t* cidx = (idx_t*)alloc((size_t)E * 4);
  float* gmax = (float*)alloc(NGRAPH * HID * 4);
  float* gsum = (float*)alloc(NGRAPH * HID * 4);
  int* gcnt   = (int*)alloc(NGRAPH * 4);

  hipMemsetAsync(cnt, 0, (size_t)N * 4, stream);
  hipMemsetAsync(fillc, 0, (size_t)N * 4, stream);
  hipMemsetAsync(gmax, 0, NGRAPH * HID * 4, stream);
  hipMemsetAsync(gsum, 0, NGRAPH * HID * 4, stream);
  hipMemsetAsync(gcnt, 0, NGRAPH * 4, stream);

  // graph structure (per launch; deterministic work)
  k_count<<<(E + 255) / 256, 256, 0, stream>>>(dstv, cnt, E);
  k_scan<<<1, 1024, 0, stream>>>(cnt, off, dinv, N);
  k_fill<<<(E + 255) / 256, 256, 0, stream>>>(srcv, dstv, off, fillc, cidx, E);

  // layer 0: 1024 -> 128
  k_gemm<1024><<<(N + 63) / 64, 256, 0, stream>>>(x, W0, bufA, N);
  k_agg<<<(N + 3) / 4, 256, 0, stream>>>(bufA, dinv, off, cidx, b0, bufB, N);
  // layer 1: 128 -> 128
  k_gemm<128><<<(N + 63) / 64, 256, 0, stream>>>(bufB, W1, bufA, N);
  k_agg<<<(N + 3) / 4, 256, 0, stream>>>(bufA, dinv, off, cidx, b1, bufB, N);
  // layer 2: 128 -> 128
  k_gemm<128><<<(N + 63) / 64, 256, 0, stream>>>(bufB, W2, bufA, N);
  k_agg<<<(N + 3) / 4, 256, 0, stream>>>(bufA, dinv, off, cidx, b2, bufB, N);

  // pooling + head
  k_gcnt<<<(N + 255) / 256, 256, 0, stream>>>(bat, gcnt, N);
  k_pool<<<(N + 127) / 128, 128, 0, stream>>>(bufB, bat, gmax, gsum, N);
  k_mlp<<<1, 256, 0, stream>>>(gmax, gsum, gcnt, Wl1, bl1, Wl2, bl2, Wl3, bl3, out);
}

// Round 2
// 461.258 us; speedup vs baseline: 1.7353x; 1.7353x over previous
//
#include <hip/hip_runtime.h>
#include <math.h>

#define HID 128
#define NGRAPH 4

typedef int idx_t;
typedef short bf16x8 __attribute__((ext_vector_type(8)));
typedef float f32x4 __attribute__((ext_vector_type(4)));

__device__ inline ushort f2bf(float f) {
  uint u = __float_as_uint(f);
  u += 0x7FFF + ((u >> 16) & 1);   // RNE
  return (ushort)(u >> 16);
}
__device__ inline float bf2f(ushort h) { return __uint_as_float(((uint)h) << 16); }

// swizzled element offset into a [rows][32] ushort LDS tile (16B slots)
__device__ inline int sw(int row, int slot) {
  return (row << 5) + ((slot ^ ((row >> 1) & 3)) << 3);
}

// ---------------- degree histogram ----------------
__global__ __launch_bounds__(256) void k_count(const idx_t* __restrict__ dst,
                                               int* __restrict__ cnt, int E) {
  int e = blockIdx.x * 256 + threadIdx.x;
  if (e < E) atomicAdd(&cnt[dst[e]], 1);
}

// ---------------- hierarchical exclusive scan ----------------
#define SC 1024  // elements per scan block (256 thr x 4)
__global__ __launch_bounds__(256) void k_scan1(const int* __restrict__ cnt,
                                               int* __restrict__ bsum, int n) {
  __shared__ int sh[256];
  int base = blockIdx.x * SC + threadIdx.x * 4;
  int s = 0;
#pragma unroll
  for (int j = 0; j < 4; ++j) { int i = base + j; if (i < n) s += cnt[i]; }
  sh[threadIdx.x] = s;
  __syncthreads();
  for (int o = 128; o > 0; o >>= 1) {
    if (threadIdx.x < o) sh[threadIdx.x] += sh[threadIdx.x + o];
    __syncthreads();
  }
  if (threadIdx.x == 0) bsum[blockIdx.x] = sh[0];
}

__global__ __launch_bounds__(64) void k_scan2(const int* __restrict__ bsum,
                                              int* __restrict__ boff,
                                              int* __restrict__ off, int nb, int n) {
  int lane = threadIdx.x;
  int v = (lane < nb) ? bsum[lane] : 0;
  for (int d = 1; d < 64; d <<= 1) {
    int t = __shfl_up(v, d);
    if (lane >= d) v += t;
  }
  int ex = __shfl_up(v, 1);
  if (lane == 0) ex = 0;
  if (lane < nb) boff[lane] = ex;
  if (lane == nb - 1) off[n] = v;  // grand total
}

__global__ __launch_bounds__(256) void k_scan3(const int* __restrict__ cnt,
                                               const int* __restrict__ boff,
                                               int* __restrict__ off,
                                               float* __restrict__ dinv, int n) {
  __shared__ int sh[256];
  int base = blockIdx.x * SC + threadIdx.x * 4;
  int c[4];
  int s = 0;
#pragma unroll
  for (int j = 0; j < 4; ++j) {
    int i = base + j;
    c[j] = (i < n) ? cnt[i] : 0;
    s += c[j];
  }
  sh[threadIdx.x] = s;
  __syncthreads();
  for (int o = 1; o < 256; o <<= 1) {
    int t = (threadIdx.x >= (unsigned)o) ? sh[threadIdx.x - o] : 0;
    __syncthreads();
    sh[threadIdx.x] += t;
    __syncthreads();
  }
  int ex = sh[threadIdx.x] - s + boff[blockIdx.x];
#pragma unroll
  for (int j = 0; j < 4; ++j) {
    int i = base + j;
    if (i < n) {
      off[i] = ex;
      dinv[i] = 1.0f / sqrtf((float)c[j] + 1.0f);  // deg + self-loop
      ex += c[j];
    }
  }
}

// ---------------- CSR fill ----------------
__global__ __launch_bounds__(256) void k_fill(const idx_t* __restrict__ src,
                                              const idx_t* __restrict__ dst,
                                              const int* __restrict__ off,
                                              int* __restrict__ fillc,
                                              idx_t* __restrict__ cidx, int E) {
  int e = blockIdx.x * 256 + threadIdx.x;
  if (e < E) {
    int d = dst[e];
    int p = atomicAdd(&fillc[d], 1);
    cidx[off[d] + p] = src[e];
  }
}

// ---------------- W split: fp32 [K][128] -> bf16 hi/lo transposed [128][K] ----
__global__ __launch_bounds__(256) void k_wsplit(const float* __restrict__ W,
                                                ushort* __restrict__ Wh,
                                                ushort* __restrict__ Wl, int K) {
  int i = blockIdx.x * 256 + threadIdx.x;
  if (i >= K * HID) return;
  int k = i >> 7, n = i & 127;
  float f = W[i];
  ushort h = f2bf(f);
  Wh[(size_t)n * K + k] = h;
  Wl[(size_t)n * K + k] = f2bf(f - bf2f(h));
}

// ---------------- split-bf16 MFMA GEMM: Y[M][128] = X[M][K] @ W[K][128] -----
// 3-pass hi/lo: Ah*Bh + Ah*Bl + Al*Bh  (error ~2^-16 relative)
template <int K>
__global__ __launch_bounds__(256) void k_gemm_mfma(const float* __restrict__ X,
                                                   const ushort* __restrict__ Wh,
                                                   const ushort* __restrict__ Wl,
                                                   float* __restrict__ Y, int M) {
  __shared__ __align__(16) ushort Ah[128 * 32];
  __shared__ __align__(16) ushort Al[128 * 32];
  __shared__ __align__(16) ushort Bh[128 * 32];
  __shared__ __align__(16) ushort Bl[128 * 32];
  int tid = threadIdx.x;
  int wid = tid >> 6, lane = tid & 63;
  int lrow = lane & 15, kg = lane >> 4;  // frag row/col within 16, k-group 0..3
  int row0 = blockIdx.x * 128;
  f32x4 acc[2][8] = {};

  for (int k0 = 0; k0 < K; k0 += 32) {
    // stage A: 128 rows x 32 k, fp32 -> bf16 hi/lo in registers
#pragma unroll
    for (int p = 0; p < 2; ++p) {
      int g = tid + (p << 8);       // 0..511
      int r = g >> 2, s = g & 3;    // row, 8-elem slot
      int grow = row0 + r;
      float xv[8] = {0.f, 0.f, 0.f, 0.f, 0.f, 0.f, 0.f, 0.f};
      if (grow < M) {
        const float4 v0 = *(const float4*)&X[(size_t)grow * K + k0 + s * 8];
        const float4 v1 = *(const float4*)&X[(size_t)grow * K + k0 + s * 8 + 4];
        xv[0] = v0.x; xv[1] = v0.y; xv[2] = v0.z; xv[3] = v0.w;
        xv[4] = v1.x; xv[5] = v1.y; xv[6] = v1.z; xv[7] = v1.w;
      }
      bf16x8 hv, lv;
#pragma unroll
      for (int j = 0; j < 8; ++j) {
        ushort hb = f2bf(xv[j]);
        hv[j] = (short)hb;
        lv[j] = (short)f2bf(xv[j] - bf2f(hb));
      }
      *(bf16x8*)&Ah[sw(r, s)] = hv;
      *(bf16x8*)&Al[sw(r, s)] = lv;
    }
    // stage B: 128 cols x 32 k from pre-split transposed W (bf16)
#pragma unroll
    for (int p = 0; p < 2; ++p) {
      int g = tid + (p << 8);
      int c = g >> 2, s = g & 3;
      *(bf16x8*)&Bh[sw(c, s)] = *(const bf16x8*)&Wh[(size_t)c * K + k0 + s * 8];
      *(bf16x8*)&Bl[sw(c, s)] = *(const bf16x8*)&Wl[(size_t)c * K + k0 + s * 8];
    }
    __syncthreads();

    bf16x8 ah[2], al[2];
#pragma unroll
    for (int mi = 0; mi < 2; ++mi) {
      int r = wid * 32 + mi * 16 + lrow;
      ah[mi] = *(const bf16x8*)&Ah[sw(r, kg)];
      al[mi] = *(const bf16x8*)&Al[sw(r, kg)];
    }
#pragma unroll
    for (int ni = 0; ni < 8; ++ni) {
      int c = ni * 16 + lrow;
      bf16x8 bh = *(const bf16x8*)&Bh[sw(c, kg)];
      bf16x8 bl = *(const bf16x8*)&Bl[sw(c, kg)];
#pragma unroll
      for (int mi = 0; mi < 2; ++mi) {
        acc[mi][ni] = __builtin_amdgcn_mfma_f32_16x16x32_bf16(ah[mi], bh, acc[mi][ni], 0, 0, 0);
        acc[mi][ni] = __builtin_amdgcn_mfma_f32_16x16x32_bf16(al[mi], bh, acc[mi][ni], 0, 0, 0);
        acc[mi][ni] = __builtin_amdgcn_mfma_f32_16x16x32_bf16(ah[mi], bl, acc[mi][ni], 0, 0, 0);
      }
    }
    __syncthreads();
  }
  // epilogue: C frag row=(lane>>4)*4+reg, col=lane&15
#pragma unroll
  for (int mi = 0; mi < 2; ++mi)
#pragma unroll
    for (int ni = 0; ni < 8; ++ni)
#pragma unroll
      for (int r = 0; r < 4; ++r) {
        int grow = row0 + wid * 32 + mi * 16 + kg * 4 + r;
        if (grow < M) Y[(size_t)grow * HID + ni * 16 + lrow] = acc[mi][ni][r];
      }
}

// ---------------- per-node gather-aggregate + bias + ReLU (unroll-4) --------
__global__ __launch_bounds__(256) void k_agg(const float* __restrict__ xw,
                                             const float* __restrict__ dinv,
                                             const int* __restrict__ off,
                                             const idx_t* __restrict__ cidx,
                                             const float* __restrict__ bias,
                                             float* __restrict__ out, int n) {
  int v = blockIdx.x * 4 + (threadIdx.x >> 6);
  if (v >= n) return;
  int lane = threadIdx.x & 63;
  size_t lb = (size_t)lane * 2;
  float dv = dinv[v];
  float2 self = *reinterpret_cast<const float2*>(&xw[(size_t)v * HID + lb]);
  float ax = dv * dv * self.x;
  float ay = dv * dv * self.y;
  int j0 = off[v], j1 = off[v + 1];
  int j = j0;
  for (; j + 4 <= j1; j += 4) {
    int u0 = cidx[j], u1 = cidx[j + 1], u2 = cidx[j + 2], u3 = cidx[j + 3];
    float w0 = dinv[u0] * dv, w1 = dinv[u1] * dv, w2 = dinv[u2] * dv, w3 = dinv[u3] * dv;
    float2 m0 = *reinterpret_cast<const float2*>(&xw[(size_t)u0 * HID + lb]);
    float2 m1 = *reinterpret_cast<const float2*>(&xw[(size_t)u1 * HID + lb]);
    float2 m2 = *reinterpret_cast<const float2*>(&xw[(size_t)u2 * HID + lb]);
    float2 m3 = *reinterpret_cast<const float2*>(&xw[(size_t)u3 * HID + lb]);
    ax = fmaf(w0, m0.x, ax); ay = fmaf(w0, m0.y, ay);
    ax = fmaf(w1, m1.x, ax); ay = fmaf(w1, m1.y, ay);
    ax = fmaf(w2, m2.x, ax); ay = fmaf(w2, m2.y, ay);
    ax = fmaf(w3, m3.x, ax); ay = fmaf(w3, m3.y, ay);
  }
  for (; j < j1; ++j) {
    int u = cidx[j];
    float w = dinv[u] * dv;
    float2 m = *reinterpret_cast<const float2*>(&xw[(size_t)u * HID + lb]);
    ax = fmaf(w, m.x, ax); ay = fmaf(w, m.y, ay);
  }
  float2 b = *reinterpret_cast<const float2*>(&bias[lb]);
  float2 o;
  o.x = fmaxf(ax + b.x, 0.0f);
  o.y = fmaxf(ay + b.y, 0.0f);
  *reinterpret_cast<float2*>(&out[(size_t)v * HID + lb]) = o;
}

// ---------------- per-graph node counts ----------------
__global__ __launch_bounds__(256) void k_gcnt(const idx_t* __restrict__ batch,
                                              int* __restrict__ gcnt, int n) {
  __shared__ int h[NGRAPH];
  int tid = threadIdx.x;
  if (tid < NGRAPH) h[tid] = 0;
  __syncthreads();
  int i = blockIdx.x * 256 + tid;
  if (i < n) atomicAdd(&h[batch[i]], 1);
  __syncthreads();
  if (tid < NGRAPH && h[tid]) atomicAdd(&gcnt[tid], h[tid]);
}

// ---------------- segment max+sum pooling (batch sorted) ----------------
__global__ __launch_bounds__(128) void k_pool(const float* __restrict__ h,
                                              const idx_t* __restrict__ batch,
                                              float* __restrict__ gmax,
                                              float* __restrict__ gsum, int n) {
  int f = threadIdx.x;
  int v0 = blockIdx.x * 128;
  int cur = -1;
  float mx = 0.f, sm = 0.f;
  for (int i = 0; i < 128; ++i) {
    int v = v0 + i;
    if (v >= n) break;
    int g = batch[v];
    if (g != cur) {
      if (cur >= 0) {
        atomicMax((int*)&gmax[cur * HID + f], __float_as_int(mx));  // h>=0
        atomicAdd(&gsum[cur * HID + f], sm);
      }
      cur = g; mx = 0.f; sm = 0.f;
    }
    float val = h[(size_t)v * HID + f];
    mx = fmaxf(mx, val);
    sm += val;
  }
  if (cur >= 0) {
    atomicMax((int*)&gmax[cur * HID + f], __float_as_int(mx));
    atomicAdd(&gsum[cur * HID + f], sm);
  }
}

// ---------------- tiny MLP head (one block) ----------------
__global__ __launch_bounds__(256) void k_mlp(const float* __restrict__ gmax,
                                             const float* __restrict__ gsum,
                                             const int* __restrict__ gcnt,
                                             const float* __restrict__ Wl1,
                                             const float* __restrict__ bl1,
                                             const float* __restrict__ Wl2,
                                             const float* __restrict__ bl2,
                                             const float* __restrict__ Wl3,
                                             const float* __restrict__ bl3,
                                             float* __restrict__ out) {
  __shared__ float G[NGRAPH][2 * HID];
  __shared__ float H1[NGRAPH][HID];
  __shared__ float H2[NGRAPH][HID / 2];
  int t = threadIdx.x;
  for (int i = t; i < NGRAPH * 2 * HID; i += 256) {
    int gi = i >> 8, j = i & 255;
    float val;
    if (j < HID) val = gmax[gi * HID + j];
    else val = gsum[gi * HID + (j - HID)] / fmaxf((float)gcnt[gi], 1.0f);
    G[gi][j] = val;
  }
  __syncthreads();
  for (int i = t; i < NGRAPH * HID; i += 256) {
    int gi = i >> 7, j = i & 127;
    float a = bl1[j];
    for (int k = 0; k < 2 * HID; ++k) a = fmaf(G[gi][k], Wl1[k * HID + j], a);
    H1[gi][j] = fmaxf(a, 0.f);
  }
  __syncthreads();
  {
    int gi = t >> 6, j = t & 63;
    float a = bl2[j];
    for (int k = 0; k < HID; ++k) a = fmaf(H1[gi][k], Wl2[k * 64 + j], a);
    H2[gi][j] = fmaxf(a, 0.f);
  }
  __syncthreads();
  if (t < NGRAPH) {
    float a = bl3[0];
    for (int k = 0; k < 64; ++k) a = fmaf(H2[t][k], Wl3[k], a);
    out[t] = fminf(a, 5.0f);
  }
}

extern "C" void kernel_launch(void* const* d_in, const int* in_sizes, int n_in,
                              void* d_out, int out_size, void* d_ws, size_t ws_size,
                              hipStream_t stream) {
  const float* x   = (const float*)d_in[0];
  const idx_t* ei  = (const idx_t*)d_in[1];
  const idx_t* bat = (const idx_t*)d_in[2];
  const float* W0 = (const float*)d_in[3];  const float* b0 = (const float*)d_in[4];
  const float* W1 = (const float*)d_in[5];  const float* b1 = (const float*)d_in[6];
  const float* W2 = (const float*)d_in[7];  const float* b2 = (const float*)d_in[8];
  const float* Wl1 = (const float*)d_in[9];  const float* bl1 = (const float*)d_in[10];
  const float* Wl2 = (const float*)d_in[11]; const float* bl2 = (const float*)d_in[12];
  const float* Wl3 = (const float*)d_in[13]; const float* bl3 = (const float*)d_in[14];
  float* out = (float*)d_out;

  const int N = in_sizes[2];
  const int E = in_sizes[1] / 2;
  const idx_t* srcv = ei;
  const idx_t* dstv = ei + E;
  const int nb = (N + SC - 1) / SC;  // 49 scan blocks (<=64)

  char* ws = (char*)d_ws;
  size_t o = 0;
  auto alloc = [&](size_t bytes) -> void* {
    void* p = ws + o;
    o = (o + bytes + 255) & ~(size_t)255;
    return p;
  };
  float* bufA = (float*)alloc((size_t)N * HID * 4);   // xw
  float* bufB = (float*)alloc((size_t)N * HID * 4);   // h (post-relu)
  float* dinv = (float*)alloc((size_t)N * 4);
  int* cnt    = (int*)alloc((size_t)N * 4);
  int* off    = (int*)alloc((size_t)(N + 1) * 4);
  int* fillc  = (int*)alloc((size_t)N * 4);
  idx_t* cidx = (idx_t*)alloc((size_t)E * 4);
  int* bsum   = (int*)alloc(64 * 4);
  int* boff   = (int*)alloc(64 * 4);
  ushort* Wh0 = (ushort*)alloc((size_t)1024 * HID * 2);
  ushort* Wl0 = (ushort*)alloc((size_t)1024 * HID * 2);
  ushort* Wh1 = (ushort*)alloc((size_t)HID * HID * 2);
  ushort* Wlo1 = (ushort*)alloc((size_t)HID * HID * 2);
  ushort* Wh2 = (ushort*)alloc((size_t)HID * HID * 2);
  ushort* Wlo2 = (ushort*)alloc((size_t)HID * HID * 2);
  float* gmax = (float*)alloc(NGRAPH * HID * 4);
  float* gsum = (float*)alloc(NGRAPH * HID * 4);
  int* gcnt   = (int*)alloc(NGRAPH * 4);

  hipMemsetAsync(cnt, 0, (size_t)N * 4, stream);
  hipMemsetAsync(fillc, 0, (size_t)N * 4, stream);
  hipMemsetAsync(gmax, 0, NGRAPH * HID * 4, stream);
  hipMemsetAsync(gsum, 0, NGRAPH * HID * 4, stream);
  hipMemsetAsync(gcnt, 0, NGRAPH * 4, stream);

  // weight splits (tiny)
  k_wsplit<<<(1024 * HID + 255) / 256, 256, 0, stream>>>(W0, Wh0, Wl0, 1024);
  k_wsplit<<<(HID * HID + 255) / 256, 256, 0, stream>>>(W1, Wh1, Wlo1, HID);
  k_wsplit<<<(HID * HID + 255) / 256, 256, 0, stream>>>(W2, Wh2, Wlo2, HID);

  // CSR build
  k_count<<<(E + 255) / 256, 256, 0, stream>>>(dstv, cnt, E);
  k_scan1<<<nb, 256, 0, stream>>>(cnt, bsum, N);
  k_scan2<<<1, 64, 0, stream>>>(bsum, boff, off, nb, N);
  k_scan3<<<nb, 256, 0, stream>>>(cnt, boff, off, dinv, N);
  k_fill<<<(E + 255) / 256, 256, 0, stream>>>(srcv, dstv, off, fillc, cidx, E);

  const int gblk = (N + 127) / 128;
  // layer 0: 1024 -> 128
  k_gemm_mfma<1024><<<gblk, 256, 0, stream>>>(x, Wh0, Wl0, bufA, N);
  k_agg<<<(N + 3) / 4, 256, 0, stream>>>(bufA, dinv, off, cidx, b0, bufB, N);
  // layer 1
  k_gemm_mfma<HID><<<gblk, 256, 0, stream>>>(bufB, Wh1, Wlo1, bufA, N);
  k_agg<<<(N + 3) / 4, 256, 0, stream>>>(bufA, dinv, off, cidx, b1, bufB, N);
  // layer 2
  k_gemm_mfma<HID><<<gblk, 256, 0, stream>>>(bufB, Wh2, Wlo2, bufA, N);
  k_agg<<<(N + 3) / 4, 256, 0, stream>>>(bufA, dinv, off, cidx, b2, bufB, N);

  // pooling + head
  k_gcnt<<<(N + 255) / 256, 256, 0, stream>>>(bat, gcnt, N);
  k_pool<<<(N + 127) / 128, 128, 0, stream>>>(bufB, bat, gmax, gsum, N);
  k_mlp<<<1, 256, 0, stream>>>(gmax, gsum, gcnt, Wl1, bl1, Wl2, bl2, Wl3, bl3, out);
}

// Round 3
// 458.121 us; speedup vs baseline: 1.7472x; 1.0068x over previous
//
#include <hip/hip_runtime.h>
#include <math.h>

#define HID 128
#define NGRAPH 4

typedef int idx_t;
typedef short bf16x8 __attribute__((ext_vector_type(8)));
typedef float f32x4 __attribute__((ext_vector_type(4)));

__device__ inline ushort f2bf(float f) {
  uint u = __float_as_uint(f);
  u += 0x7FFF + ((u >> 16) & 1);   // RNE
  return (ushort)(u >> 16);
}
__device__ inline float bf2f(ushort h) { return __uint_as_float(((uint)h) << 16); }

// swizzled element offset into a [rows][32] ushort LDS tile (16B slots)
__device__ inline int sw(int row, int slot) {
  return (row << 5) + ((slot ^ ((row >> 1) & 3)) << 3);
}

// ---------------- degree histogram ----------------
__global__ __launch_bounds__(256) void k_count(const idx_t* __restrict__ dst,
                                               int* __restrict__ cnt, int E) {
  int e = blockIdx.x * 256 + threadIdx.x;
  if (e < E) atomicAdd(&cnt[dst[e]], 1);
}

// ---------------- hierarchical exclusive scan ----------------
#define SC 1024  // elements per scan block (256 thr x 4)
__global__ __launch_bounds__(256) void k_scan1(const int* __restrict__ cnt,
                                               int* __restrict__ bsum, int n) {
  __shared__ int sh[256];
  int base = blockIdx.x * SC + threadIdx.x * 4;
  int s = 0;
#pragma unroll
  for (int j = 0; j < 4; ++j) { int i = base + j; if (i < n) s += cnt[i]; }
  sh[threadIdx.x] = s;
  __syncthreads();
  for (int o = 128; o > 0; o >>= 1) {
    if (threadIdx.x < o) sh[threadIdx.x] += sh[threadIdx.x + o];
    __syncthreads();
  }
  if (threadIdx.x == 0) bsum[blockIdx.x] = sh[0];
}

__global__ __launch_bounds__(64) void k_scan2(const int* __restrict__ bsum,
                                              int* __restrict__ boff,
                                              int* __restrict__ off, int nb, int n) {
  int lane = threadIdx.x;
  int v = (lane < nb) ? bsum[lane] : 0;
  for (int d = 1; d < 64; d <<= 1) {
    int t = __shfl_up(v, d);
    if (lane >= d) v += t;
  }
  int ex = __shfl_up(v, 1);
  if (lane == 0) ex = 0;
  if (lane < nb) boff[lane] = ex;
  if (lane == nb - 1) off[n] = v;  // grand total
}

__global__ __launch_bounds__(256) void k_scan3(const int* __restrict__ cnt,
                                               const int* __restrict__ boff,
                                               int* __restrict__ off,
                                               float* __restrict__ dinv, int n) {
  __shared__ int sh[256];
  int base = blockIdx.x * SC + threadIdx.x * 4;
  int c[4];
  int s = 0;
#pragma unroll
  for (int j = 0; j < 4; ++j) {
    int i = base + j;
    c[j] = (i < n) ? cnt[i] : 0;
    s += c[j];
  }
  sh[threadIdx.x] = s;
  __syncthreads();
  for (int o = 1; o < 256; o <<= 1) {
    int t = (threadIdx.x >= (unsigned)o) ? sh[threadIdx.x - o] : 0;
    __syncthreads();
    sh[threadIdx.x] += t;
    __syncthreads();
  }
  int ex = sh[threadIdx.x] - s + boff[blockIdx.x];
#pragma unroll
  for (int j = 0; j < 4; ++j) {
    int i = base + j;
    if (i < n) {
      off[i] = ex;
      dinv[i] = 1.0f / sqrtf((float)c[j] + 1.0f);  // deg + self-loop
      ex += c[j];
    }
  }
}

// ---------------- CSR fill: packed (src, weight) per edge ----------------
__global__ __launch_bounds__(256) void k_fill(const idx_t* __restrict__ src,
                                              const idx_t* __restrict__ dst,
                                              const int* __restrict__ off,
                                              const float* __restrict__ dinv,
                                              int* __restrict__ fillc,
                                              int2* __restrict__ edata, int E) {
  int e = blockIdx.x * 256 + threadIdx.x;
  if (e < E) {
    int s = src[e], d = dst[e];
    int p = atomicAdd(&fillc[d], 1);
    float w = dinv[s] * dinv[d];
    edata[off[d] + p] = make_int2(s, __float_as_int(w));
  }
}

// ---------------- W split: fp32 [K][128] -> bf16 hi/lo transposed [128][K] ----
__global__ __launch_bounds__(256) void k_wsplit(const float* __restrict__ W,
                                                ushort* __restrict__ Wh,
                                                ushort* __restrict__ Wl, int K) {
  int i = blockIdx.x * 256 + threadIdx.x;
  if (i >= K * HID) return;
  int k = i >> 7, n = i & 127;
  float f = W[i];
  ushort h = f2bf(f);
  Wh[(size_t)n * K + k] = h;
  Wl[(size_t)n * K + k] = f2bf(f - bf2f(h));
}

// ---------------- split-bf16 MFMA GEMM: Y[M][128] = X[M][K] @ W[K][128] -----
// 3-pass hi/lo: Ah*Bh + Ah*Bl + Al*Bh  (error ~2^-16 relative)
template <int K>
__global__ __launch_bounds__(256) void k_gemm_mfma(const float* __restrict__ X,
                                                   const ushort* __restrict__ Wh,
                                                   const ushort* __restrict__ Wl,
                                                   float* __restrict__ Y, int M) {
  __shared__ __align__(16) ushort Ah[128 * 32];
  __shared__ __align__(16) ushort Al[128 * 32];
  __shared__ __align__(16) ushort Bh[128 * 32];
  __shared__ __align__(16) ushort Bl[128 * 32];
  int tid = threadIdx.x;
  int wid = tid >> 6, lane = tid & 63;
  int lrow = lane & 15, kg = lane >> 4;  // frag row/col within 16, k-group 0..3
  int row0 = blockIdx.x * 128;
  f32x4 acc[2][8] = {};

  for (int k0 = 0; k0 < K; k0 += 32) {
    // stage A: 128 rows x 32 k, fp32 -> bf16 hi/lo in registers
#pragma unroll
    for (int p = 0; p < 2; ++p) {
      int g = tid + (p << 8);       // 0..511
      int r = g >> 2, s = g & 3;    // row, 8-elem slot
      int grow = row0 + r;
      float xv[8] = {0.f, 0.f, 0.f, 0.f, 0.f, 0.f, 0.f, 0.f};
      if (grow < M) {
        const float4 v0 = *(const float4*)&X[(size_t)grow * K + k0 + s * 8];
        const float4 v1 = *(const float4*)&X[(size_t)grow * K + k0 + s * 8 + 4];
        xv[0] = v0.x; xv[1] = v0.y; xv[2] = v0.z; xv[3] = v0.w;
        xv[4] = v1.x; xv[5] = v1.y; xv[6] = v1.z; xv[7] = v1.w;
      }
      bf16x8 hv, lv;
#pragma unroll
      for (int j = 0; j < 8; ++j) {
        ushort hb = f2bf(xv[j]);
        hv[j] = (short)hb;
        lv[j] = (short)f2bf(xv[j] - bf2f(hb));
      }
      *(bf16x8*)&Ah[sw(r, s)] = hv;
      *(bf16x8*)&Al[sw(r, s)] = lv;
    }
    // stage B: 128 cols x 32 k from pre-split transposed W (bf16)
#pragma unroll
    for (int p = 0; p < 2; ++p) {
      int g = tid + (p << 8);
      int c = g >> 2, s = g & 3;
      *(bf16x8*)&Bh[sw(c, s)] = *(const bf16x8*)&Wh[(size_t)c * K + k0 + s * 8];
      *(bf16x8*)&Bl[sw(c, s)] = *(const bf16x8*)&Wl[(size_t)c * K + k0 + s * 8];
    }
    __syncthreads();

    bf16x8 ah[2], al[2];
#pragma unroll
    for (int mi = 0; mi < 2; ++mi) {
      int r = wid * 32 + mi * 16 + lrow;
      ah[mi] = *(const bf16x8*)&Ah[sw(r, kg)];
      al[mi] = *(const bf16x8*)&Al[sw(r, kg)];
    }
#pragma unroll
    for (int ni = 0; ni < 8; ++ni) {
      int c = ni * 16 + lrow;
      bf16x8 bh = *(const bf16x8*)&Bh[sw(c, kg)];
      bf16x8 bl = *(const bf16x8*)&Bl[sw(c, kg)];
#pragma unroll
      for (int mi = 0; mi < 2; ++mi) {
        acc[mi][ni] = __builtin_amdgcn_mfma_f32_16x16x32_bf16(ah[mi], bh, acc[mi][ni], 0, 0, 0);
        acc[mi][ni] = __builtin_amdgcn_mfma_f32_16x16x32_bf16(al[mi], bh, acc[mi][ni], 0, 0, 0);
        acc[mi][ni] = __builtin_amdgcn_mfma_f32_16x16x32_bf16(ah[mi], bl, acc[mi][ni], 0, 0, 0);
      }
    }
    __syncthreads();
  }
  // epilogue: C frag row=(lane>>4)*4+reg, col=lane&15
#pragma unroll
  for (int mi = 0; mi < 2; ++mi)
#pragma unroll
    for (int ni = 0; ni < 8; ++ni)
#pragma unroll
      for (int r = 0; r < 4; ++r) {
        int grow = row0 + wid * 32 + mi * 16 + kg * 4 + r;
        if (grow < M) Y[(size_t)grow * HID + ni * 16 + lrow] = acc[mi][ni][r];
      }
}

// ---------------- per-node gather-aggregate + bias + ReLU -------------------
// One wave per node. Virtual item list: item0 = self (w=dv*dv), item t>=1 =
// neighbor t-1 (w precomputed in edata). Lanes 0-31 take even items, lanes
// 32-63 odd items; each half-wave loads a full 128-float row as float4/lane.
__global__ __launch_bounds__(256) void k_agg(const float* __restrict__ xw,
                                             const float* __restrict__ dinv,
                                             const int* __restrict__ off,
                                             const int2* __restrict__ edata,
                                             const float* __restrict__ bias,
                                             float* __restrict__ out, int n) {
  int v = blockIdx.x * 4 + (threadIdx.x >> 6);
  if (v >= n) return;
  int lane = threadIdx.x & 63;
  int half = lane >> 5;
  int fl = (lane & 31) * 4;   // feature offset for this lane's float4
  int j0 = off[v], j1 = off[v + 1];
  int T = (j1 - j0) + 1;      // neighbors + self
  float dv = dinv[v];

  float4 acc;
  {  // peel item `half`: half0 -> self, half1 -> first neighbor (if any)
    int u = v;
    float w = (half == 0) ? dv * dv : 0.0f;
    if (half == 1 && T > 1) {
      int2 e = edata[j0];
      u = e.x;
      w = __int_as_float(e.y);
    }
    const float4 m = *(const float4*)&xw[(size_t)u * HID + fl];
    acc.x = w * m.x; acc.y = w * m.y; acc.z = w * m.z; acc.w = w * m.w;
  }
  int t = 2 + half;
  for (; t + 2 < T; t += 4) {  // two items per half-wave per iteration
    int2 e0 = edata[j0 + t - 1];
    int2 e1 = edata[j0 + t + 1];
    float w0 = __int_as_float(e0.y), w1 = __int_as_float(e1.y);
    const float4 m0 = *(const float4*)&xw[(size_t)e0.x * HID + fl];
    const float4 m1 = *(const float4*)&xw[(size_t)e1.x * HID + fl];
    acc.x = fmaf(w0, m0.x, acc.x); acc.y = fmaf(w0, m0.y, acc.y);
    acc.z = fmaf(w0, m0.z, acc.z); acc.w = fmaf(w0, m0.w, acc.w);
    acc.x = fmaf(w1, m1.x, acc.x); acc.y = fmaf(w1, m1.y, acc.y);
    acc.z = fmaf(w1, m1.z, acc.z); acc.w = fmaf(w1, m1.w, acc.w);
  }
  if (t < T) {
    int2 e = edata[j0 + t - 1];
    float w = __int_as_float(e.y);
    const float4 m = *(const float4*)&xw[(size_t)e.x * HID + fl];
    acc.x = fmaf(w, m.x, acc.x); acc.y = fmaf(w, m.y, acc.y);
    acc.z = fmaf(w, m.z, acc.z); acc.w = fmaf(w, m.w, acc.w);
  }
  // combine the two half-waves
  acc.x += __shfl_xor(acc.x, 32);
  acc.y += __shfl_xor(acc.y, 32);
  acc.z += __shfl_xor(acc.z, 32);
  acc.w += __shfl_xor(acc.w, 32);
  if (half == 0) {
    const float4 b = *(const float4*)&bias[fl];
    float4 o;
    o.x = fmaxf(acc.x + b.x, 0.0f);
    o.y = fmaxf(acc.y + b.y, 0.0f);
    o.z = fmaxf(acc.z + b.z, 0.0f);
    o.w = fmaxf(acc.w + b.w, 0.0f);
    *(float4*)&out[(size_t)v * HID + fl] = o;
  }
}

// ---------------- per-graph node counts ----------------
__global__ __launch_bounds__(256) void k_gcnt(const idx_t* __restrict__ batch,
                                              int* __restrict__ gcnt, int n) {
  __shared__ int h[NGRAPH];
  int tid = threadIdx.x;
  if (tid < NGRAPH) h[tid] = 0;
  __syncthreads();
  int i = blockIdx.x * 256 + tid;
  if (i < n) atomicAdd(&h[batch[i]], 1);
  __syncthreads();
  if (tid < NGRAPH && h[tid]) atomicAdd(&gcnt[tid], h[tid]);
}

// ---------------- segment max+sum pooling (batch sorted) ----------------
__global__ __launch_bounds__(128) void k_pool(const float* __restrict__ h,
                                              const idx_t* __restrict__ batch,
                                              float* __restrict__ gmax,
                                              float* __restrict__ gsum, int n) {
  int f = threadIdx.x;
  int v0 = blockIdx.x * 128;
  int cur = -1;
  float mx = 0.f, sm = 0.f;
  for (int i = 0; i < 128; ++i) {
    int v = v0 + i;
    if (v >= n) break;
    int g = batch[v];
    if (g != cur) {
      if (cur >= 0) {
        atomicMax((int*)&gmax[cur * HID + f], __float_as_int(mx));  // h>=0
        atomicAdd(&gsum[cur * HID + f], sm);
      }
      cur = g; mx = 0.f; sm = 0.f;
    }
    float val = h[(size_t)v * HID + f];
    mx = fmaxf(mx, val);
    sm += val;
  }
  if (cur >= 0) {
    atomicMax((int*)&gmax[cur * HID + f], __float_as_int(mx));
    atomicAdd(&gsum[cur * HID + f], sm);
  }
}

// ---------------- tiny MLP head (one block) ----------------
__global__ __launch_bounds__(256) void k_mlp(const float* __restrict__ gmax,
                                             const float* __restrict__ gsum,
                                             const int* __restrict__ gcnt,
                                             const float* __restrict__ Wl1,
                                             const float* __restrict__ bl1,
                                             const float* __restrict__ Wl2,
                                             const float* __restrict__ bl2,
                                             const float* __restrict__ Wl3,
                                             const float* __restrict__ bl3,
                                             float* __restrict__ out) {
  __shared__ float G[NGRAPH][2 * HID];
  __shared__ float H1[NGRAPH][HID];
  __shared__ float H2[NGRAPH][HID / 2];
  int t = threadIdx.x;
  for (int i = t; i < NGRAPH * 2 * HID; i += 256) {
    int gi = i >> 8, j = i & 255;
    float val;
    if (j < HID) val = gmax[gi * HID + j];
    else val = gsum[gi * HID + (j - HID)] / fmaxf((float)gcnt[gi], 1.0f);
    G[gi][j] = val;
  }
  __syncthreads();
  for (int i = t; i < NGRAPH * HID; i += 256) {
    int gi = i >> 7, j = i & 127;
    float a = bl1[j];
    for (int k = 0; k < 2 * HID; ++k) a = fmaf(G[gi][k], Wl1[k * HID + j], a);
    H1[gi][j] = fmaxf(a, 0.f);
  }
  __syncthreads();
  {
    int gi = t >> 6, j = t & 63;
    float a = bl2[j];
    for (int k = 0; k < HID; ++k) a = fmaf(H1[gi][k], Wl2[k * 64 + j], a);
    H2[gi][j] = fmaxf(a, 0.f);
  }
  __syncthreads();
  if (t < NGRAPH) {
    float a = bl3[0];
    for (int k = 0; k < 64; ++k) a = fmaf(H2[t][k], Wl3[k], a);
    out[t] = fminf(a, 5.0f);
  }
}

extern "C" void kernel_launch(void* const* d_in, const int* in_sizes, int n_in,
                              void* d_out, int out_size, void* d_ws, size_t ws_size,
                              hipStream_t stream) {
  const float* x   = (const float*)d_in[0];
  const idx_t* ei  = (const idx_t*)d_in[1];
  const idx_t* bat = (const idx_t*)d_in[2];
  const float* W0 = (const float*)d_in[3];  const float* b0 = (const float*)d_in[4];
  const float* W1 = (const float*)d_in[5];  const float* b1 = (const float*)d_in[6];
  const float* W2 = (const float*)d_in[7];  const float* b2 = (const float*)d_in[8];
  const float* Wl1 = (const float*)d_in[9];  const float* bl1 = (const float*)d_in[10];
  const float* Wl2 = (const float*)d_in[11]; const float* bl2 = (const float*)d_in[12];
  const float* Wl3 = (const float*)d_in[13]; const float* bl3 = (const float*)d_in[14];
  float* out = (float*)d_out;

  const int N = in_sizes[2];
  const int E = in_sizes[1] / 2;
  const idx_t* srcv = ei;
  const idx_t* dstv = ei + E;
  const int nb = (N + SC - 1) / SC;  // 49 scan blocks (<=64)

  char* ws = (char*)d_ws;
  size_t o = 0;
  auto alloc = [&](size_t bytes) -> void* {
    void* p = ws + o;
    o = (o + bytes + 255) & ~(size_t)255;
    return p;
  };
  float* bufA = (float*)alloc((size_t)N * HID * 4);   // xw
  float* bufB = (float*)alloc((size_t)N * HID * 4);   // h (post-relu)
  float* dinv = (float*)alloc((size_t)N * 4);
  int* cnt    = (int*)alloc((size_t)N * 4);
  int* off    = (int*)alloc((size_t)(N + 1) * 4);
  int* fillc  = (int*)alloc((size_t)N * 4);
  int2* edata = (int2*)alloc((size_t)E * 8);
  int* bsum   = (int*)alloc(64 * 4);
  int* boff   = (int*)alloc(64 * 4);
  ushort* Wh0 = (ushort*)alloc((size_t)1024 * HID * 2);
  ushort* Wl0 = (ushort*)alloc((size_t)1024 * HID * 2);
  ushort* Wh1 = (ushort*)alloc((size_t)HID * HID * 2);
  ushort* Wlo1 = (ushort*)alloc((size_t)HID * HID * 2);
  ushort* Wh2 = (ushort*)alloc((size_t)HID * HID * 2);
  ushort* Wlo2 = (ushort*)alloc((size_t)HID * HID * 2);
  float* gmax = (float*)alloc(NGRAPH * HID * 4);
  float* gsum = (float*)alloc(NGRAPH * HID * 4);
  int* gcnt   = (int*)alloc(NGRAPH * 4);

  hipMemsetAsync(cnt, 0, (size_t)N * 4, stream);
  hipMemsetAsync(fillc, 0, (size_t)N * 4, stream);
  hipMemsetAsync(gmax, 0, NGRAPH * HID * 4, stream);
  hipMemsetAsync(gsum, 0, NGRAPH * HID * 4, stream);
  hipMemsetAsync(gcnt, 0, NGRAPH * 4, stream);

  // weight splits (tiny)
  k_wsplit<<<(1024 * HID + 255) / 256, 256, 0, stream>>>(W0, Wh0, Wl0, 1024);
  k_wsplit<<<(HID * HID + 255) / 256, 256, 0, stream>>>(W1, Wh1, Wlo1, HID);
  k_wsplit<<<(HID * HID + 255) / 256, 256, 0, stream>>>(W2, Wh2, Wlo2, HID);

  // CSR build
  k_count<<<(E + 255) / 256, 256, 0, stream>>>(dstv, cnt, E);
  k_scan1<<<nb, 256, 0, stream>>>(cnt, bsum, N);
  k_scan2<<<1, 64, 0, stream>>>(bsum, boff, off, nb, N);
  k_scan3<<<nb, 256, 0, stream>>>(cnt, boff, off, dinv, N);
  k_fill<<<(E + 255) / 256, 256, 0, stream>>>(srcv, dstv, off, dinv, fillc, edata, E);

  const int gblk = (N + 127) / 128;
  // layer 0: 1024 -> 128
  k_gemm_mfma<1024><<<gblk, 256, 0, stream>>>(x, Wh0, Wl0, bufA, N);
  k_agg<<<(N + 3) / 4, 256, 0, stream>>>(bufA, dinv, off, edata, b0, bufB, N);
  // layer 1
  k_gemm_mfma<HID><<<gblk, 256, 0, stream>>>(bufB, Wh1, Wlo1, bufA, N);
  k_agg<<<(N + 3) / 4, 256, 0, stream>>>(bufA, dinv, off, edata, b1, bufB, N);
  // layer 2
  k_gemm_mfma<HID><<<gblk, 256, 0, stream>>>(bufB, Wh2, Wlo2, bufA, N);
  k_agg<<<(N + 3) / 4, 256, 0, stream>>>(bufA, dinv, off, edata, b2, bufB, N);

  // pooling + head
  k_gcnt<<<(N + 255) / 256, 256, 0, stream>>>(bat, gcnt, N);
  k_pool<<<(N + 127) / 128, 128, 0, stream>>>(bufB, bat, gmax, gsum, N);
  k_mlp<<<1, 256, 0, stream>>>(gmax, gsum, gcnt, Wl1, bl1, Wl2, bl2, Wl3, bl3, out);
}